// Round 9
// baseline (144.488 us; speedup 1.0000x reference)
//
#include <hip/hip_runtime.h>
#include <cstdint>

#define B_ 8
#define T_ 1024
#define C_ 512
#define H_ 8

typedef __attribute__((ext_vector_type(8))) short bf16x8;
typedef __attribute__((ext_vector_type(4))) float f32x4;

__device__ __forceinline__ unsigned short f2bf(float f) {
  uint32_t u = __float_as_uint(f);
  u += 0x7FFFu + ((u >> 16) & 1u);   // RNE; inputs never NaN
  return (unsigned short)(u >> 16);
}
__device__ __forceinline__ float bf2f(unsigned short h) {
  return __uint_as_float(((uint32_t)h) << 16);
}

// async global->LDS, 16B per lane (LDS dest = wave-uniform base + lane*16)
__device__ __forceinline__ void gload16(const void* g, void* lds) {
  __builtin_amdgcn_global_load_lds(
      (const __attribute__((address_space(1))) void*)g,
      (__attribute__((address_space(3))) void*)lds, 16, 0, 0);
}

// ---------------------------------------------------------------------------
// Fused prep: blocks [0,4096) cvt x; [4096,4864) cvt 3 weights; [4864,4928)
// transpose+cvt w2 [64][1024] -> w2t [1024][64]. Block-uniform branches.
// ---------------------------------------------------------------------------
__global__ __launch_bounds__(256) void prep_all(
    const float* __restrict__ x, const float* __restrict__ w1,
    const float* __restrict__ vw, const float* __restrict__ pw,
    const float* __restrict__ w2,
    unsigned short* __restrict__ xb, unsigned short* __restrict__ w1b,
    unsigned short* __restrict__ vwb, unsigned short* __restrict__ pjb,
    unsigned short* __restrict__ w2t)
{
  __shared__ float tile[32][33];
  const int bb = blockIdx.x, t = threadIdx.x;
  if (bb < 4096) {
    int i = bb * 256 + t;                       // exactly 1048576 float4 units
    float4 f = reinterpret_cast<const float4*>(x)[i];
    uint2 o;
    o.x = (uint32_t)f2bf(f.x) | ((uint32_t)f2bf(f.y) << 16);
    o.y = (uint32_t)f2bf(f.z) | ((uint32_t)f2bf(f.w) << 16);
    reinterpret_cast<uint2*>(xb)[i] = o;
  } else if (bb < 4864) {
    int seg = (bb - 4096) >> 8;
    int i = ((bb - 4096) & 255) * 256 + t;      // 65536 units per 512x512
    const float* in = (seg == 0) ? w1 : (seg == 1) ? vw : pw;
    unsigned short* o = (seg == 0) ? w1b : (seg == 1) ? vwb : pjb;
    float4 f = reinterpret_cast<const float4*>(in)[i];
    uint2 u;
    u.x = (uint32_t)f2bf(f.x) | ((uint32_t)f2bf(f.y) << 16);
    u.y = (uint32_t)f2bf(f.z) | ((uint32_t)f2bf(f.w) << 16);
    reinterpret_cast<uint2*>(o)[i] = u;
  } else {
    int tt = bb - 4864;                         // 64 tiles: 32 in k, 2 in dd
    int c0 = (tt & 31) * 32, r0 = (tt >> 5) * 32;
    int ri = t >> 3, ci = (t & 7) * 4;
    float4 f = *reinterpret_cast<const float4*>(&w2[(size_t)(r0 + ri) * 1024 + c0 + ci]);
    tile[ri][ci] = f.x; tile[ri][ci + 1] = f.y;
    tile[ri][ci + 2] = f.z; tile[ri][ci + 3] = f.w;
    __syncthreads();
    int co = t >> 3, ro = (t & 7) * 4;
    uint2 o;
    o.x = (uint32_t)f2bf(tile[ro][co])     | ((uint32_t)f2bf(tile[ro + 1][co]) << 16);
    o.y = (uint32_t)f2bf(tile[ro + 2][co]) | ((uint32_t)f2bf(tile[ro + 3][co]) << 16);
    *reinterpret_cast<uint2*>(&w2t[(size_t)(c0 + co) * 64 + r0 + ro]) = o;
  }
}

// ---------------------------------------------------------------------------
// Fused dual GEMM: rb = relu(x@w1^T+b1), vT = (x@vw^T+bv)^T.
// BM=64, BN=64, BK=64, 4 waves (2x2 of 32x32), grid (8,128)=1024 blocks ->
// 4 blocks/CU (24KB LDS, single-buffered m97-style 2-barrier loop).
// Occupancy/TLP hides the staging drain (m114 wave-level overlap).
// ---------------------------------------------------------------------------
__global__ __launch_bounds__(256) void gemm_w1v(
    const unsigned short* __restrict__ xb,
    const unsigned short* __restrict__ w1b, const unsigned short* __restrict__ vwb,
    const float* __restrict__ w1_bias, const float* __restrict__ v_bias,
    unsigned short* __restrict__ rb, unsigned short* __restrict__ vT)
{
  __shared__ alignas(16) unsigned short Xs[64 * 64];    // 8KB
  __shared__ alignas(16) unsigned short W1s[64 * 64];   // 8KB
  __shared__ alignas(16) unsigned short Vs[64 * 64];    // 8KB

  const int tid = threadIdx.x;
  const int lane = tid & 63, w = tid >> 6;
  const int l15 = lane & 15, g4 = lane >> 4;
  const int wr = w >> 1, wc = w & 1;
  const int n0 = blockIdx.x * 64;
  const int m0 = blockIdx.y * 64;
  const int lrow = lane >> 3, lcol = (lane & 7) * 8;

  f32x4 a1[2][2] = {};
  f32x4 a2[2][2] = {};

  for (int t = 0; t < 8; ++t) {
    const int k0 = t * 64;
    __syncthreads();                    // previous tile's consumers done
    #pragma unroll
    for (int cc = 0; cc < 6; ++cc) {    // 24 chunks / 4 waves
      int c = w * 6 + cc;
      if (c < 8)
        gload16(&xb[(size_t)(m0 + c * 8 + lrow) * 512 + k0 + lcol], (char*)Xs + c * 1024);
      else if (c < 16)
        gload16(&w1b[(size_t)(n0 + (c - 8) * 8 + lrow) * 512 + k0 + lcol],
                (char*)W1s + (c - 8) * 1024);
      else
        gload16(&vwb[(size_t)(n0 + (c - 16) * 8 + lrow) * 512 + k0 + lcol],
                (char*)Vs + (c - 16) * 1024);
    }
    __syncthreads();                    // vmcnt drained -> staged data visible

    #pragma unroll
    for (int ks = 0; ks < 2; ++ks) {
      bf16x8 af[2], wf[2], vf[2];
      #pragma unroll
      for (int i = 0; i < 2; ++i)
        af[i] = *(const bf16x8*)((const char*)Xs +
                 (wr * 32 + 16 * i + l15) * 128 + ks * 64 + g4 * 16);
      #pragma unroll
      for (int j = 0; j < 2; ++j) {
        int n = wc * 32 + 16 * j + l15;
        wf[j] = *(const bf16x8*)((const char*)W1s + n * 128 + ks * 64 + g4 * 16);
        vf[j] = *(const bf16x8*)((const char*)Vs  + n * 128 + ks * 64 + g4 * 16);
      }
      #pragma unroll
      for (int i = 0; i < 2; ++i)
        #pragma unroll
        for (int j = 0; j < 2; ++j) {
          a1[i][j] = __builtin_amdgcn_mfma_f32_16x16x32_bf16(af[i], wf[j], a1[i][j], 0, 0, 0);
          a2[i][j] = __builtin_amdgcn_mfma_f32_16x16x32_bf16(af[i], vf[j], a2[i][j], 0, 0, 0);
        }
    }
  }

  // epilogue: C/D map col=lane&15 (n), row=(lane>>4)*4+reg (m)  [m89/m91]
  #pragma unroll
  for (int i = 0; i < 2; ++i) {
    int mb = m0 + wr * 32 + 16 * i + g4 * 4;
    #pragma unroll
    for (int j = 0; j < 2; ++j) {
      int n = n0 + wc * 32 + 16 * j + l15;
      float b1 = w1_bias[n];
      #pragma unroll
      for (int rg = 0; rg < 4; ++rg)
        rb[(size_t)(mb + rg) * 512 + n] = f2bf(fmaxf(a1[i][j][rg] + b1, 0.f));
      float bv = v_bias[n];
      unsigned short p[4];
      #pragma unroll
      for (int rg = 0; rg < 4; ++rg) p[rg] = f2bf(a2[i][j][rg] + bv);
      *reinterpret_cast<uint2*>(&vT[(size_t)n * 8192 + mb]) =
          *reinterpret_cast<const uint2*>(p);
    }
  }
}

// ---------------------------------------------------------------------------
// proj GEMM: out_f32 = ya@proj^T + b. BM=BN=64, grid (8,128)=1024 blocks,
// 16KB LDS -> occupancy-bound by grid (4/CU), single-buffered.
// ---------------------------------------------------------------------------
__global__ __launch_bounds__(256) void gemm_proj(
    const unsigned short* __restrict__ A, const unsigned short* __restrict__ Wb,
    const float* __restrict__ bias, float* __restrict__ out)
{
  __shared__ alignas(16) unsigned short As[64 * 64];    // 8KB
  __shared__ alignas(16) unsigned short Ws[64 * 64];    // 8KB

  const int tid = threadIdx.x;
  const int lane = tid & 63, w = tid >> 6;
  const int l15 = lane & 15, g4 = lane >> 4;
  const int wr = w >> 1, wc = w & 1;
  const int n0 = blockIdx.x * 64;
  const int m0 = blockIdx.y * 64;
  const int lrow = lane >> 3, lcol = (lane & 7) * 8;

  f32x4 acc[2][2] = {};

  for (int t = 0; t < 8; ++t) {
    const int k0 = t * 64;
    __syncthreads();
    #pragma unroll
    for (int cc = 0; cc < 4; ++cc) {    // 16 chunks / 4 waves
      int c = w * 4 + cc;
      if (c < 8)
        gload16(&A[(size_t)(m0 + c * 8 + lrow) * 512 + k0 + lcol], (char*)As + c * 1024);
      else
        gload16(&Wb[(size_t)(n0 + (c - 8) * 8 + lrow) * 512 + k0 + lcol],
                (char*)Ws + (c - 8) * 1024);
    }
    __syncthreads();

    #pragma unroll
    for (int ks = 0; ks < 2; ++ks) {
      bf16x8 af[2], wf[2];
      #pragma unroll
      for (int i = 0; i < 2; ++i)
        af[i] = *(const bf16x8*)((const char*)As +
                 (wr * 32 + 16 * i + l15) * 128 + ks * 64 + g4 * 16);
      #pragma unroll
      for (int j = 0; j < 2; ++j)
        wf[j] = *(const bf16x8*)((const char*)Ws +
                 (wc * 32 + 16 * j + l15) * 128 + ks * 64 + g4 * 16);
      #pragma unroll
      for (int i = 0; i < 2; ++i)
        #pragma unroll
        for (int j = 0; j < 2; ++j)
          acc[i][j] = __builtin_amdgcn_mfma_f32_16x16x32_bf16(af[i], wf[j], acc[i][j], 0, 0, 0);
    }
  }

  #pragma unroll
  for (int i = 0; i < 2; ++i) {
    int mb = m0 + wr * 32 + 16 * i + g4 * 4;
    #pragma unroll
    for (int j = 0; j < 2; ++j) {
      int n = n0 + wc * 32 + 16 * j + l15;
      float bj = bias[n];
      #pragma unroll
      for (int rg = 0; rg < 4; ++rg)
        out[(size_t)(mb + rg) * 512 + n] = acc[i][j][rg] + bj;
    }
  }
}

// ---------------------------------------------------------------------------
// MFMA synthesizer attention, v3: one q-tile per block, 1024 blocks with LPT
// dispatch (qt=15 blocks first), single-buffered W2/Vt (~37KB -> 4 blocks/CU).
// Swapped GEMM1 (lane holds 4 consecutive k of its own q row -> packed b64
// E-stores), b2 via direct float4 loads, ones-row MFMA row sums, rel-pos path
// collapsed to 5 diagonal taps. Reg prefetch of next tile's W2/V.
// ---------------------------------------------------------------------------
#define SA_VLOAD(K0)                                                                  \
  do {                                                                                \
    { int c = tid;       int row = c >> 3, sl = c & 7;                                \
      w0 = *reinterpret_cast<const uint4*>(&w2t[(size_t)((K0) + row) * 64 + sl * 8]); } \
    { int c = tid + 256; int row = c >> 3, sl = c & 7;                                \
      w1 = *reinterpret_cast<const uint4*>(&w2t[(size_t)((K0) + row) * 64 + sl * 8]); } \
    { int c = tid;       int row = c >> 3, sl = c & 7;                                \
      v0 = *reinterpret_cast<const uint4*>(&vT[(size_t)(h * 64 + row) * 8192 + b * 1024 + (K0) + sl * 8]); } \
    { int c = tid + 256; int row = c >> 3, sl = c & 7;                                \
      v1 = *reinterpret_cast<const uint4*>(&vT[(size_t)(h * 64 + row) * 8192 + b * 1024 + (K0) + sl * 8]); } \
  } while (0)

#define SA_VSTORE()                                                                   \
  do {                                                                                \
    { int c = tid;       int row = c >> 3, sl = c & 7;                                \
      *reinterpret_cast<uint4*>(W2 + row * 128 + ((sl ^ (row & 7)) << 4)) = w0; }     \
    { int c = tid + 256; int row = c >> 3, sl = c & 7;                                \
      *reinterpret_cast<uint4*>(W2 + row * 128 + ((sl ^ (row & 7)) << 4)) = w1; }     \
    { int c = tid;       int row = c >> 3, sl = c & 7;                                \
      *reinterpret_cast<uint4*>(Vt + row * 128 + ((sl ^ (row & 7)) << 4)) = v0; }     \
    { int c = tid + 256; int row = c >> 3, sl = c & 7;                                \
      *reinterpret_cast<uint4*>(Vt + row * 128 + ((sl ^ (row & 7)) << 4)) = v1; }     \
  } while (0)

__global__ __launch_bounds__(256) void synth_attn_mfma(
    const unsigned short* __restrict__ rb, const unsigned short* __restrict__ vT,
    const unsigned short* __restrict__ w2t, const float* __restrict__ b2,
    const float* __restrict__ table, unsigned short* __restrict__ ya)
{
  __shared__ alignas(16) unsigned short RtS[64 * 64];   // 8KB  [q][dd]
  __shared__ alignas(16) unsigned short ElS[64 * 64];   // 8KB  [q][k]
  __shared__ alignas(16) unsigned short W2S[64 * 64];   // 8KB  [k][dd]
  __shared__ alignas(16) unsigned short VtS[80 * 64];   // 10KB [dd][k]+ones
  __shared__ float tap[64][5];
  __shared__ float tabs[6][64];

  char* Rt = (char*)RtS;
  char* El = (char*)ElS;
  char* W2 = (char*)W2S;
  char* Vt = (char*)VtS;

  const int tid = threadIdx.x;
  const int lane = tid & 63, w = tid >> 6;
  const int l15 = lane & 15, g = lane >> 4;
  const int bid = blockIdx.x;
  const int qt = 15 - (bid >> 6);      // LPT: heaviest q-tiles dispatch first
  const int bh = bid & 63;
  const int b = bh >> 3, h = bh & 7;
  const int q0 = qt * 64;
  const int qrl = 16 * w + l15;        // this lane's local q row (0..63)
  const int sx = l15 & 7;              // row-swizzle term (row&7 for our rows)

  #pragma unroll
  for (int t2 = 0; t2 < 2; ++t2) {
    int idx = tid + t2 * 256;
    if (idx < 384) ((float*)tabs)[idx] = table[idx];
  }
  {  // ones/zeros rows 64..79 of Vt (unswizzled: rows are constant-valued)
    int row = 64 + (tid >> 4), ch = tid & 15;
    uint2 val;
    val.x = (row == 64) ? 0x3F803F80u : 0u;
    val.y = val.x;
    *reinterpret_cast<uint2*>(Vt + row * 128 + ch * 8) = val;
  }
  // stage R tile once (bf16 copy with slot swizzle)
  #pragma unroll
  for (int t2 = 0; t2 < 2; ++t2) {
    int c = tid + t2 * 256; int row = c >> 3, sl = c & 7;
    uint4 d = *reinterpret_cast<const uint4*>(
        &rb[(size_t)(b * 1024 + q0 + row) * 512 + h * 64 + sl * 8]);
    *reinterpret_cast<uint4*>(Rt + row * 128 + ((sl ^ (row & 7)) << 4)) = d;
  }
  if (lane < 16) {
    int qr = w * 16 + lane;
    #pragma unroll
    for (int jj = 0; jj < 5; ++jj) tap[qr][jj] = 0.f;
  }

  f32x4 acc[4] = {};
  f32x4 accS = {};

  uint4 w0, w1, v0, v1;
  SA_VLOAD(0);

  for (int kt = 0; kt <= qt; ++kt) {
    const int k0 = kt * 64;
    __syncthreads();               // previous tile's W2/Vt/El consumers done
    SA_VSTORE();
    if (kt < qt) SA_VLOAD(k0 + 64);   // issue next-tile global loads early
    // b2 values this lane needs: k = k0 + 16j + 4g + rr (L1-broadcast loads)
    float4 bq0 = *reinterpret_cast<const float4*>(&b2[k0 +  0 + 4 * g]);
    float4 bq1 = *reinterpret_cast<const float4*>(&b2[k0 + 16 + 4 * g]);
    float4 bq2 = *reinterpret_cast<const float4*>(&b2[k0 + 32 + 4 * g]);
    float4 bq3 = *reinterpret_cast<const float4*>(&b2[k0 + 48 + 4 * g]);
    __syncthreads();               // staged W2/Vt (+Rt on iter 0) visible

    // ---- GEMM1 swapped: mfma(A=W2 rows k, B=Rt rows q) -> lane holds
    //      S[k=k0+16j+4g+rr][q=q0+qrl]  (4 consecutive k per register) ----
    bf16x8 rb0 = *(const bf16x8*)(Rt + qrl * 128 + ((g ^ sx) << 4));
    bf16x8 rb1 = *(const bf16x8*)(Rt + qrl * 128 + (((4 + g) ^ sx) << 4));
    f32x4 sf[4] = {};
    #pragma unroll
    for (int j = 0; j < 4; ++j) {
      int ar = 16 * j + l15;          // ar & 7 == sx
      bf16x8 wa0 = *(const bf16x8*)(W2 + ar * 128 + ((g ^ sx) << 4));
      bf16x8 wa1 = *(const bf16x8*)(W2 + ar * 128 + (((4 + g) ^ sx) << 4));
      sf[j] = __builtin_amdgcn_mfma_f32_16x16x32_bf16(wa0, rb0, sf[j], 0, 0, 0);
      sf[j] = __builtin_amdgcn_mfma_f32_16x16x32_bf16(wa1, rb1, sf[j], 0, 0, 0);
    }

    // ---- exp + pack 4 bf16 -> one b64 store per j ----
    const bool diag = (kt == qt);
    #pragma unroll
    for (int j = 0; j < 4; ++j) {
      const float4 bq = (j == 0) ? bq0 : (j == 1) ? bq1 : (j == 2) ? bq2 : bq3;
      const int kb = 16 * j + 4 * g;
      float e0 = __expf(sf[j][0] + bq.x);
      float e1 = __expf(sf[j][1] + bq.y);
      float e2 = __expf(sf[j][2] + bq.z);
      float e3 = __expf(sf[j][3] + bq.w);
      if (diag) {
        e0 = (kb + 0 <= qrl) ? e0 : 0.f;
        e1 = (kb + 1 <= qrl) ? e1 : 0.f;
        e2 = (kb + 2 <= qrl) ? e2 : 0.f;
        e3 = (kb + 3 <= qrl) ? e3 : 0.f;
      }
      uint2 pk;
      pk.x = (uint32_t)f2bf(e0) | ((uint32_t)f2bf(e1) << 16);
      pk.y = (uint32_t)f2bf(e2) | ((uint32_t)f2bf(e3) << 16);
      int slot = (2 * j + (g >> 1)) ^ sx;
      *reinterpret_cast<uint2*>(El + qrl * 128 + slot * 16 + (g & 1) * 8) = pk;
    }

    // ---- GEMM2: acc += E @ V ; ones-row MFMA -> exact row sums ----
    bf16x8 ae0 = *(const bf16x8*)(El + qrl * 128 + ((g ^ sx) << 4));
    bf16x8 ae1 = *(const bf16x8*)(El + qrl * 128 + (((4 + g) ^ sx) << 4));
    #pragma unroll
    for (int j = 0; j < 4; ++j) {
      int vr = 16 * j + l15;          // vr & 7 == sx
      bf16x8 vb0 = *(const bf16x8*)(Vt + vr * 128 + ((g ^ sx) << 4));
      bf16x8 vb1 = *(const bf16x8*)(Vt + vr * 128 + (((4 + g) ^ sx) << 4));
      acc[j] = __builtin_amdgcn_mfma_f32_16x16x32_bf16(ae0, vb0, acc[j], 0, 0, 0);
      acc[j] = __builtin_amdgcn_mfma_f32_16x16x32_bf16(ae1, vb1, acc[j], 0, 0, 0);
    }
    {
      int orow = 64 + l15;            // orow & 7 == sx; rows constant-valued
      bf16x8 o0 = *(const bf16x8*)(Vt + orow * 128 + ((g ^ sx) << 4));
      bf16x8 o1 = *(const bf16x8*)(Vt + orow * 128 + (((4 + g) ^ sx) << 4));
      accS = __builtin_amdgcn_mfma_f32_16x16x32_bf16(ae0, o0, accS, 0, 0, 0);
      accS = __builtin_amdgcn_mfma_f32_16x16x32_bf16(ae1, o1, accS, 0, 0, 0);
    }

    // ---- 5 diagonal taps (collapsed rel-pos path) ----
    if (lane < 16) {
      int qr = w * 16 + lane;
      int off = q0 + qr - 4 - k0;
      #pragma unroll
      for (int jj = 0; jj < 5; ++jj) {
        int kk = off + jj;
        if ((unsigned)kk < 64u) {
          int byte = qr * 128 + ((((kk >> 3) ^ (qr & 7)) << 4) | ((kk & 7) << 1));
          tap[qr][jj] += bf2f(*reinterpret_cast<unsigned short*>(El + byte));
        }
      }
    }
  }

  // ---- epilogue ----
  float inv[4], tp[4][5];
  #pragma unroll
  for (int rr = 0; rr < 4; ++rr) {
    float ls = __shfl(accS[rr], lane & 48, 64);   // l15==0 lane of this group
    inv[rr] = 1.f / ls;
    int qr = w * 16 + g * 4 + rr;
    #pragma unroll
    for (int jj = 0; jj < 5; ++jj) tp[rr][jj] = tap[qr][jj] * inv[rr];
  }
  #pragma unroll
  for (int j = 0; j < 4; ++j) {
    int dd = 16 * j + l15;
    float t0 = tabs[0][dd];
    float dt[5];
    #pragma unroll
    for (int jj = 0; jj < 5; ++jj) dt[jj] = tabs[jj + 1][dd] - t0;
    #pragma unroll
    for (int rr = 0; rr < 4; ++rr) {
      int qr = w * 16 + g * 4 + rr;
      float y = acc[j][rr] * inv[rr] + t0;
      #pragma unroll
      for (int jj = 0; jj < 5; ++jj) y = fmaf(tp[rr][jj], dt[jj], y);
      ya[(size_t)(b * 1024 + q0 + qr) * 512 + h * 64 + dd] = f2bf(y);
    }
  }
}

// ---------------------------------------------------------------------------
extern "C" void kernel_launch(void* const* d_in, const int* in_sizes, int n_in,
                              void* d_out, int out_size, void* d_ws, size_t ws_size,
                              hipStream_t stream) {
  const float* x      = (const float*)d_in[0];
  const float* w1_w   = (const float*)d_in[1];
  const float* w1_b   = (const float*)d_in[2];
  const float* w2     = (const float*)d_in[3];
  const float* b2     = (const float*)d_in[4];
  const float* v_w    = (const float*)d_in[5];
  const float* v_b    = (const float*)d_in[6];
  const float* proj_w = (const float*)d_in[7];
  const float* proj_b = (const float*)d_in[8];
  const float* relv   = (const float*)d_in[9];
  float* out = (float*)d_out;

  const size_t buf = (size_t)B_ * T_ * C_;   // 4.19M elems
  const size_t wsz = (size_t)C_ * C_;
  unsigned short* rb    = (unsigned short*)d_ws;   // relu(w1(x))  [8192][512]
  unsigned short* vT    = rb + buf;                // v^T          [512][8192]
  unsigned short* xb    = vT + buf;                // x bf16       [8192][512]
  unsigned short* yab   = xb + buf;                // attn out     [8192][512]
  unsigned short* w1b   = yab + buf;
  unsigned short* vwb   = w1b + wsz;
  unsigned short* projb = vwb + wsz;
  unsigned short* w2t   = projb + wsz;             // w2^T [1024][64]

  prep_all<<<4928, 256, 0, stream>>>(x, w1_w, v_w, proj_w, w2,
                                     xb, w1b, vwb, projb, w2t);

  gemm_w1v<<<dim3(8, 128), 256, 0, stream>>>(xb, w1b, vwb, w1_b, v_b, rb, vT);

  synth_attn_mfma<<<1024, 256, 0, stream>>>(rb, vT, w2t, b2, relv, yab);

  gemm_proj<<<dim3(8, 128), 256, 0, stream>>>(yab, projb, proj_b, out);
}